// Round 10
// baseline (280.855 us; speedup 1.0000x reference)
//
#include <hip/hip_runtime.h>
#include <stdint.h>

typedef unsigned short u16;
typedef __attribute__((ext_vector_type(8))) short short8;
typedef __attribute__((ext_vector_type(4))) float f32x4;

#define KD 4096

typedef const __attribute__((address_space(1))) void* gas1_t;
typedef __attribute__((address_space(3))) void* las3_t;

__device__ __forceinline__ void g2l16(const void* g, void* l) {
  __builtin_amdgcn_global_load_lds((gas1_t)g, (las3_t)l, 16, 0, 0);
}

// round-to-nearest-even fp32 -> bf16 (finite inputs)
__device__ __forceinline__ u16 f2bf(float f) {
  uint32_t u = __float_as_uint(f);
  return (u16)((u + 0x7FFFu + ((u >> 16) & 1u)) >> 16);
}

// ---- fused conversion (UNCHANGED -- control variable):
//   blocks [0, 4096):     q_int [K][N] int32 -> Qt [N][K] bf16 (zp pre-subtracted)
//   blocks [4096, 20480): x fp32 -> bf16 elementwise
__global__ __launch_bounds__(256)
void cvt_fused(const float4* __restrict__ x, const int* __restrict__ q,
               const int* __restrict__ zp, uint2* __restrict__ xb,
               u16* __restrict__ qt) {
  const int b = blockIdx.x;
  if (b >= 4096) {
    int gid = (b - 4096) * 256 + threadIdx.x;
    float4 f = x[gid];
    union { u16 u[4]; uint2 v; } o;
    o.u[0] = f2bf(f.x); o.u[1] = f2bf(f.y);
    o.u[2] = f2bf(f.z); o.u[3] = f2bf(f.w);
    xb[gid] = o.v;
    return;
  }
  __shared__ uint32_t P[32][68];  // [k_pair][n], stride 272B (16B-aligned)
  const int n0 = (b & 63) * 64;
  const int k0 = (b >> 6) * 64;
  const int nc = threadIdx.x & 15;
  const int kr = threadIdx.x >> 4;

  int z[4];
#pragma unroll
  for (int j = 0; j < 4; ++j) z[j] = zp[n0 + nc * 4 + j];

#pragma unroll
  for (int s = 0; s < 2; ++s) {
    const int kp = kr + s * 16;
    const int64_t rb = (int64_t)(k0 + kp * 2) * KD + n0 + nc * 4;
    int4 r0 = *(const int4*)(q + rb);
    int4 r1 = *(const int4*)(q + rb + KD);
    uint4 w;
    w.x = (uint32_t)f2bf((float)(r0.x - z[0])) | ((uint32_t)f2bf((float)(r1.x - z[0])) << 16);
    w.y = (uint32_t)f2bf((float)(r0.y - z[1])) | ((uint32_t)f2bf((float)(r1.y - z[1])) << 16);
    w.z = (uint32_t)f2bf((float)(r0.z - z[2])) | ((uint32_t)f2bf((float)(r1.z - z[2])) << 16);
    w.w = (uint32_t)f2bf((float)(r0.w - z[3])) | ((uint32_t)f2bf((float)(r1.w - z[3])) << 16);
    *(uint4*)&P[kp][nc * 4] = w;
  }
  __syncthreads();

  const int kq = threadIdx.x & 7;
  const int nn = threadIdx.x >> 3;
#pragma unroll
  for (int p = 0; p < 2; ++p) {
    const int n = nn + p * 32;
    uint4 v;
    v.x = P[kq * 4 + 0][n];
    v.y = P[kq * 4 + 1][n];
    v.z = P[kq * 4 + 2][n];
    v.w = P[kq * 4 + 3][n];
    *(uint4*)(qt + (int64_t)(n0 + n) * KD + k0 + kq * 8) = v;
  }
}

// ---------------- GEMM: 256x256 tile, 6-barrier/tile (3 phases) ----------------
// A  : [M][K] bf16 row-major      Bt : [N][K] bf16 row-major
// C[m][n] = (sum_k A[m][k]*Bt[n][k]) * scale[n] + bias[n]
//
// Per K-tile, staging tile t+1 (R7 quarter layout):
//   ph0: RD A-half0 + B-lo | stage B0,B1,A0 |              BAR lgkm0 MFMA(0,0) BAR
//   ph1: RD B-hi           | stage B2,B3,A2 | vmcnt(6)     BAR lgkm0 MFMA(0,2) BAR
//   ph2: RD A-half1        | stage A1,A3    | vmcnt(2)     BAR lgkm0 MFMA(4,0)+(4,2) BAR
// The old ph3 barrier-pair ordered nothing (no reads/stages) -- removed.
// Steady-state in-flight invariant entering each tile: {A1,A3} of tile t.
// vmcnt(6)@ph1 drains t's A1,A3 (for ph2's RD_A1); vmcnt(2)@ph2 drains
// t+1's first-six before the publication barrier. No SCHED0 / LGKM8:
// loads are compiler-visible, let the backend schedule counted lgkm drains.
__global__ __launch_bounds__(512, 2)
void gemm8(const u16* __restrict__ A, const u16* __restrict__ Bt,
           const float* __restrict__ scale, const float* __restrict__ bias,
           float* __restrict__ C) {
  __shared__ u16 lds[65536];  // buf0: A@0 B@16384 | buf1: A@32768 B@49152

  const int tid = threadIdx.x;
  const int orig = blockIdx.x;
  const int lid = (orig & 7) * 32 + (orig >> 3);   // bijective XCD swizzle
  const int bm0 = (lid >> 4) * 256;
  const int bn0 = (lid & 15) * 256;

  const int lane = tid & 63;
  const int w = tid >> 6;
  const int wr = w >> 2;       // 0..1
  const int wc = w & 3;        // 0..3
  const int l15 = lane & 15;
  const int q4 = lane >> 4;    // 0..3
  const int l7 = l15 & 7;      // read-side swizzle key

  const int rl = tid >> 3;
  const int csw = (tid & 7) ^ (rl & 7);            // write-side swizzle (inverse)
  const u16* gA = A + (int64_t)(bm0 + rl) * KD + csw * 8;
  const u16* gB = Bt + (int64_t)(bn0 + rl) * KD + csw * 8;

#define STA(OFF, qq, kt) g2l16(gA + (int64_t)(qq) * 64 * KD + (kt), &lds[(OFF) + (qq) * 4096 + tid * 8])
#define STB(OFF, qq, kt) g2l16(gB + (int64_t)(qq) * 64 * KD + (kt), &lds[(OFF) + (qq) * 4096 + tid * 8])

#define RD_A(AOFF, mh)                                                        \
  do {                                                                        \
    _Pragma("unroll") for (int m = 0; m < 4; ++m) {                           \
      const int row = wr * 128 + (mh) * 64 + m * 16 + l15;                    \
      _Pragma("unroll") for (int kk = 0; kk < 2; ++kk)                        \
        ar[m][kk] = *(const short8*)&lds[(AOFF) + row * 64 + (((kk * 4 + q4) ^ l7) * 8)]; \
    }                                                                         \
  } while (0)

#define RD_B(BOFF, nn0)                                                       \
  do {                                                                        \
    _Pragma("unroll") for (int n = 0; n < 2; ++n) {                           \
      const int col = wc * 64 + ((nn0) + n) * 16 + l15;                       \
      _Pragma("unroll") for (int kk = 0; kk < 2; ++kk)                        \
        br[(nn0) + n][kk] = *(const short8*)&lds[(BOFF) + col * 64 + (((kk * 4 + q4) ^ l7) * 8)]; \
    }                                                                         \
  } while (0)

#define MFMA_Q(mb, nn0)                                                       \
  do {                                                                        \
    __builtin_amdgcn_s_setprio(1);                                            \
    _Pragma("unroll") for (int m = 0; m < 4; ++m)                             \
      _Pragma("unroll") for (int n = 0; n < 2; ++n)                           \
        _Pragma("unroll") for (int kk = 0; kk < 2; ++kk)                      \
          acc[(mb) + m][(nn0) + n] = __builtin_amdgcn_mfma_f32_16x16x32_bf16( \
              ar[m][kk], br[(nn0) + n][kk], acc[(mb) + m][(nn0) + n], 0, 0, 0); \
    __builtin_amdgcn_s_setprio(0);                                            \
  } while (0)

#define BAR __builtin_amdgcn_s_barrier()
#define LGKM0 asm volatile("s_waitcnt lgkmcnt(0)" ::: "memory")
#define VMC6 asm volatile("s_waitcnt vmcnt(6)" ::: "memory")
#define VMC2 asm volatile("s_waitcnt vmcnt(2)" ::: "memory")
#define VMC0 asm volatile("s_waitcnt vmcnt(0)" ::: "memory")
#define WNONE

// One K-tile; W1 at ph1, W2 at merged ph2 (both before their barrier).
#define K_TILE(AOFF, BOFF, SAOFF, SBOFF, KTN, STG, W1, W2)                    \
  do {                                                                        \
    /* ph0 */                                                                 \
    RD_A(AOFF, 0);                                                            \
    RD_B(BOFF, 0);                                                            \
    if (STG) { STB(SBOFF, 0, KTN); STB(SBOFF, 1, KTN); STA(SAOFF, 0, KTN); }  \
    BAR; LGKM0;                                                               \
    MFMA_Q(0, 0);                                                             \
    BAR;                                                                      \
    /* ph1 */                                                                 \
    RD_B(BOFF, 2);                                                            \
    if (STG) { STB(SBOFF, 2, KTN); STB(SBOFF, 3, KTN); STA(SAOFF, 2, KTN); }  \
    W1;                                                                       \
    BAR; LGKM0;                                                               \
    MFMA_Q(0, 2);                                                             \
    BAR;                                                                      \
    /* ph2 (merged; old ph3 barrier-pair was hazard-free) */                  \
    RD_A(AOFF, 1);                                                            \
    if (STG) { STA(SAOFF, 1, KTN); STA(SAOFF, 3, KTN); }                      \
    W2;                                                                       \
    BAR; LGKM0;                                                               \
    MFMA_Q(4, 0);                                                             \
    MFMA_Q(4, 2);                                                             \
    BAR;                                                                      \
  } while (0)

  f32x4 acc[8][4];
#pragma unroll
  for (int m = 0; m < 8; ++m)
#pragma unroll
    for (int n = 0; n < 4; ++n) acc[m][n] = (f32x4)(0.f);

  short8 ar[4][2], br[4][2];

  // ---- prologue: stage tile 0 into buf 0, consumption order; leave A1,A3 in flight
  STB(16384, 0, 0); STB(16384, 1, 0); STA(0, 0, 0);
  STB(16384, 2, 0); STB(16384, 3, 0); STA(0, 2, 0);
  STA(0, 1, 0); STA(0, 3, 0);
  VMC2;   // first-6 (B0..3, A0, A2) landed; {A1,A3} in flight (loop invariant)
  BAR;    // publication

  for (int i = 0; i < 31; ++i) {
    K_TILE(0, 16384, 32768, 49152, (2 * i + 1) * 64, 1, VMC6, VMC2);
    K_TILE(32768, 49152, 0, 16384, (2 * i + 2) * 64, 1, VMC6, VMC2);
  }
  // tile 62 (buf0), stage tile 63 -> buf1
  K_TILE(0, 16384, 32768, 49152, 63 * 64, 1, VMC6, VMC2);
  // tile 63 (buf1), no staging: VMC0 at ph1 drains its {A1,A3} before ph2 reads
  K_TILE(32768, 49152, 0, 16384, 0, 0, VMC0, WNONE);

  // ---- epilogue: out = acc*scale[col] + bias[col] ----
  const int r4 = q4 * 4;
#pragma unroll
  for (int n = 0; n < 4; ++n) {
    const int col = bn0 + wc * 64 + n * 16 + l15;
    const float sc = scale[col];
    const float bs = bias[col];
#pragma unroll
    for (int mi = 0; mi < 8; ++mi) {
      const int row = bm0 + wr * 128 + mi * 16 + r4;
#pragma unroll
      for (int j = 0; j < 4; ++j)
        C[(int64_t)(row + j) * KD + col] = acc[mi][n][j] * sc + bs;
    }
  }
}

extern "C" void kernel_launch(void* const* d_in, const int* in_sizes, int n_in,
                              void* d_out, int out_size, void* d_ws, size_t ws_size,
                              hipStream_t stream) {
  const float* x = (const float*)d_in[0];
  const int* q = (const int*)d_in[1];
  const float* scale = (const float*)d_in[2];
  const int* zp = (const int*)d_in[3];
  const float* bias = (const float*)d_in[4];
  float* out = (float*)d_out;

  u16* Xb = (u16*)d_ws;                    // 32 MiB
  u16* Qt = Xb + (size_t)4096 * 4096;      // 32 MiB

  cvt_fused<<<20480, 256, 0, stream>>>((const float4*)x, q, zp,
                                       (uint2*)Xb, Qt);

  gemm8<<<256, 512, 0, stream>>>(Xb, Qt, scale, bias, out);
}